// Round 4
// baseline (157.117 us; speedup 1.0000x reference)
//
#include <hip/hip_runtime.h>

// distance: [16, 3136, 4096] f32; score 56x56 -> bilinear resize 224x224 -> gauss sigma=4 (ksize 33)
#define NB   16
#define HW   3136
#define MEL  4096
#define SH   56
#define SW   56
#define OH   224
#define OW   224
#define KRAD 16
#define NBLK_TOPK ((NB * HW) / 4)      // 12544
#define NBLK_AT   ((SH * OH + 255) / 256)  // 49

typedef float vf4 __attribute__((ext_vector_type(4)));

// Branchless insert of v into sorted ascending triple (m0 <= m1 <= m2), keeping 3 smallest.
__device__ __forceinline__ void ins3(float v, float& m0, float& m1, float& m2) {
    float a = fminf(v, m0);
    float b = fmaxf(v, m0);
    m0 = a;
    float c = fminf(b, m1);
    float d = fmaxf(b, m1);
    m1 = c;
    m2 = fminf(d, m2);
}

// Blocks [0, NBLK_TOPK): one wave (64 lanes) per row of 4096 floats, 4 rows/block.
// All 16 global_load_dwordx4 issued up front (max MLP). Plain (temporal) loads this
// round — isolating the nontemporal flag's effect on streaming-read BW.
// Blocks [NBLK_TOPK, NBLK_TOPK+NBLK_AT): build At[56][224] (combined
// gauss∘bilinear operator), one element per thread; runs concurrently with topk.
__global__ __launch_bounds__(256, 4) void topk_score_kernel(const float* __restrict__ dist,
                                                            float* __restrict__ score,
                                                            float* __restrict__ At) {
    if (blockIdx.x >= NBLK_TOPK) {
        // ---- build At: At[j][y] = sum_k g[k] * bilinear_weight(reflect(y+k) -> coarse j) / sum(g)
        int id = (blockIdx.x - NBLK_TOPK) * 256 + threadIdx.x;
        if (id < SH * OH) {
            int j = id / OH;   // coarse index
            int y = id % OH;   // fine (output) index
            float gsum = 0.0f, acc = 0.0f;
            #pragma unroll
            for (int k = -KRAD; k <= KRAD; ++k) {
                float g = expf((float)(-k * k) * (1.0f / 32.0f));
                gsum += g;
                int f = y + k;                       // reflect at both edges
                f = (f < 0) ? -f : f;
                f = (f > OH - 1) ? (2 * (OH - 1) - f) : f;
                float sy = fmaxf((f + 0.5f) * 0.25f - 0.5f, 0.0f);
                int   y0 = (int)sy;
                float fy = sy - (float)y0;
                int   y1 = min(y0 + 1, SH - 1);
                float w = ((y0 == j) ? (1.0f - fy) : 0.0f) + ((y1 == j) ? fy : 0.0f);
                acc += g * w;
            }
            At[id] = acc / gsum;
        }
        return;
    }

    const int wid  = threadIdx.x >> 6;
    const int lane = threadIdx.x & 63;
    const long long row = (long long)blockIdx.x * 4 + wid;
    const vf4* p = (const vf4*)(dist + row * (long long)MEL);

    vf4 v[16];
    #pragma unroll
    for (int j = 0; j < 16; ++j)
        v[j] = p[lane + 64 * j];       // coalesced 1 KB/instr, contiguous 16 KB/wave

    // Two independent triples per lane to shorten the dependency chain.
    float a0 = 3.4e38f, a1 = 3.4e38f, a2 = 3.4e38f;
    float b0 = 3.4e38f, b1 = 3.4e38f, b2 = 3.4e38f;

    #pragma unroll
    for (int j = 0; j < 16; ++j) {
        ins3(v[j][0], a0, a1, a2);
        ins3(v[j][1], b0, b1, b2);
        ins3(v[j][2], a0, a1, a2);
        ins3(v[j][3], b0, b1, b2);
    }
    ins3(b0, a0, a1, a2);
    ins3(b1, a0, a1, a2);
    ins3(b2, a0, a1, a2);

    // Butterfly merge across the 64-lane wave.
    #pragma unroll
    for (int off = 32; off > 0; off >>= 1) {
        float s0 = __shfl_xor(a0, off);
        float s1 = __shfl_xor(a1, off);
        float s2 = __shfl_xor(a2, off);
        ins3(s0, a0, a1, a2);
        ins3(s1, a0, a1, a2);
        ins3(s2, a0, a1, a2);
    }

    if (lane == 0) {
        // vals = sqrt of 3 smallest distances (monotonic => selection on raw d is exact)
        float v0 = sqrtf(a0), v1 = sqrtf(a1), v2 = sqrtf(a2);
        // softmin weight of smallest: s = v0 / (1 + e^(v0-v1) + e^(v0-v2))
        score[row] = v0 / (1.0f + expf(v0 - v1) + expf(v0 - v2));
    }
}

// Fused post-process via the factored operator: out[b] = A . s[b] . A^T.
// One block per output row (b,y). A rows have <=11 nonzeros within window [w, w+11].
__global__ __launch_bounds__(256) void post_kernel(const float* __restrict__ score,
                                                   const float* __restrict__ At,
                                                   float* __restrict__ out) {
    __shared__ float tmp[SW];
    const int b = blockIdx.x / OH;
    const int y = blockIdx.x % OH;
    const int tid = threadIdx.x;
    const float* s = score + b * (SH * SW);

    // nonzero window start for fine index y (support width <= 11, window 12 covers it)
    const int wy = min(max((int)floorf((y - 15.5f) * 0.25f - 0.5f), 0), SH - 12);

    if (tid < SW) {
        float acc = 0.0f;
        #pragma unroll
        for (int t = 0; t < 12; ++t) {
            int j = wy + t;
            acc += At[j * OH + y] * s[j * SW + tid];   // At read is block-uniform
        }
        tmp[tid] = acc;
    }
    __syncthreads();

    if (tid < OW) {
        const int x = tid;
        const int wx = min(max((int)floorf((x - 15.5f) * 0.25f - 0.5f), 0), SH - 12);
        float acc = 0.0f;
        #pragma unroll
        for (int t = 0; t < 12; ++t) {
            int j = wx + t;
            acc += At[j * OH + x] * tmp[j];            // coalesced across x
        }
        out[blockIdx.x * OW + x] = acc;
    }
}

extern "C" void kernel_launch(void* const* d_in, const int* in_sizes, int n_in,
                              void* d_out, int out_size, void* d_ws, size_t ws_size,
                              hipStream_t stream) {
    const float* dist = (const float*)d_in[0];
    float* out = (float*)d_out;

    float* scorebuf = (float*)d_ws;                         // 50176 floats
    float* At       = (float*)((char*)d_ws + 50176 * 4);    // 56*224 floats

    topk_score_kernel<<<NBLK_TOPK + NBLK_AT, 256, 0, stream>>>(dist, scorebuf, At);
    post_kernel<<<NB * OH, 256, 0, stream>>>(scorebuf, At, out);
}

// Round 5
// 140.644 us; speedup vs baseline: 1.1171x; 1.1171x over previous
//
#include <hip/hip_runtime.h>

// distance: [16, 3136, 4096] f32; score 56x56 -> bilinear resize 224x224 -> gauss sigma=4 (ksize 33)
#define NB   16
#define HW   3136
#define MEL  4096
#define SH   56
#define SW   56
#define OH   224
#define OW   224
#define KRAD 16
#define NBLK_TOPK ((NB * HW) / 4)          // 12544
#define NBLK_AT   ((SH * OH + 255) / 256)  // 49

typedef float vf4 __attribute__((ext_vector_type(4)));

// Branchless insert of v into sorted ascending triple (m0 <= m1 <= m2), keeping 3 smallest.
__device__ __forceinline__ void ins3(float v, float& m0, float& m1, float& m2) {
    float a = fminf(v, m0);
    float b = fmaxf(v, m0);
    m0 = a;
    float c = fminf(b, m1);
    float d = fmaxf(b, m1);
    m1 = c;
    m2 = fminf(d, m2);
}

// Blocks [0, NBLK_TOPK): one wave (64 lanes) per row of 4096 floats, 4 rows/block.
// All 16 global_load_dwordx4 issued up front (max MLP), NONTEMPORAL — A/B-tested:
// nt gives ~5.9 TB/s vs ~5.5 TB/s without (round 3/4 isolated experiment, +12 us).
// Blocks [NBLK_TOPK, ...): build At[56][224] (gauss∘bilinear operator), one element
// per thread; rides along at the grid tail.
__global__ __launch_bounds__(256, 4) void topk_score_kernel(const float* __restrict__ dist,
                                                            float* __restrict__ score,
                                                            float* __restrict__ At) {
    if (blockIdx.x >= NBLK_TOPK) {
        // ---- build At: At[j][y] = sum_k g[k] * bilinear_weight(reflect(y+k) -> coarse j) / sum(g)
        int id = (blockIdx.x - NBLK_TOPK) * 256 + threadIdx.x;
        if (id < SH * OH) {
            int j = id / OH;   // coarse index
            int y = id % OH;   // fine (output) index
            float gsum = 0.0f, acc = 0.0f;
            #pragma unroll
            for (int k = -KRAD; k <= KRAD; ++k) {
                float g = expf((float)(-k * k) * (1.0f / 32.0f));
                gsum += g;
                int f = y + k;                       // reflect at both edges
                f = (f < 0) ? -f : f;
                f = (f > OH - 1) ? (2 * (OH - 1) - f) : f;
                float sy = fmaxf((f + 0.5f) * 0.25f - 0.5f, 0.0f);
                int   y0 = (int)sy;
                float fy = sy - (float)y0;
                int   y1 = min(y0 + 1, SH - 1);
                float w = ((y0 == j) ? (1.0f - fy) : 0.0f) + ((y1 == j) ? fy : 0.0f);
                acc += g * w;
            }
            At[id] = acc / gsum;
        }
        return;
    }

    const int wid  = threadIdx.x >> 6;
    const int lane = threadIdx.x & 63;
    const long long row = (long long)blockIdx.x * 4 + wid;
    const vf4* p = (const vf4*)(dist + row * (long long)MEL);

    vf4 v[16];
    #pragma unroll
    for (int j = 0; j < 16; ++j)
        v[j] = __builtin_nontemporal_load(p + lane + 64 * j);

    // Two independent triples per lane to shorten the dependency chain.
    float a0 = 3.4e38f, a1 = 3.4e38f, a2 = 3.4e38f;
    float b0 = 3.4e38f, b1 = 3.4e38f, b2 = 3.4e38f;

    #pragma unroll
    for (int j = 0; j < 16; ++j) {
        ins3(v[j][0], a0, a1, a2);
        ins3(v[j][1], b0, b1, b2);
        ins3(v[j][2], a0, a1, a2);
        ins3(v[j][3], b0, b1, b2);
    }
    ins3(b0, a0, a1, a2);
    ins3(b1, a0, a1, a2);
    ins3(b2, a0, a1, a2);

    // Butterfly merge across the 64-lane wave.
    #pragma unroll
    for (int off = 32; off > 0; off >>= 1) {
        float s0 = __shfl_xor(a0, off);
        float s1 = __shfl_xor(a1, off);
        float s2 = __shfl_xor(a2, off);
        ins3(s0, a0, a1, a2);
        ins3(s1, a0, a1, a2);
        ins3(s2, a0, a1, a2);
    }

    if (lane == 0) {
        // vals = sqrt of 3 smallest distances (monotonic => selection on raw d is exact)
        float v0 = sqrtf(a0), v1 = sqrtf(a1), v2 = sqrtf(a2);
        // softmin weight of smallest: s = v0 / (1 + e^(v0-v1) + e^(v0-v2))
        score[row] = v0 / (1.0f + expf(v0 - v1) + expf(v0 - v2));
    }
}

// Fused post-process via the factored operator: out[b] = A . s[b] . A^T.
// One block per output row (b,y). A rows have <=11 nonzeros within window [w, w+11].
__global__ __launch_bounds__(256) void post_kernel(const float* __restrict__ score,
                                                   const float* __restrict__ At,
                                                   float* __restrict__ out) {
    __shared__ float tmp[SW];
    const int b = blockIdx.x / OH;
    const int y = blockIdx.x % OH;
    const int tid = threadIdx.x;
    const float* s = score + b * (SH * SW);

    // nonzero window start for fine index y (support width <= 11, window 12 covers it)
    const int wy = min(max((int)floorf((y - 15.5f) * 0.25f - 0.5f), 0), SH - 12);

    if (tid < SW) {
        float acc = 0.0f;
        #pragma unroll
        for (int t = 0; t < 12; ++t) {
            int j = wy + t;
            acc += At[j * OH + y] * s[j * SW + tid];   // At read is block-uniform
        }
        tmp[tid] = acc;
    }
    __syncthreads();

    if (tid < OW) {
        const int x = tid;
        const int wx = min(max((int)floorf((x - 15.5f) * 0.25f - 0.5f), 0), SH - 12);
        float acc = 0.0f;
        #pragma unroll
        for (int t = 0; t < 12; ++t) {
            int j = wx + t;
            acc += At[j * OH + x] * tmp[j];            // coalesced across x
        }
        out[blockIdx.x * OW + x] = acc;
    }
}

extern "C" void kernel_launch(void* const* d_in, const int* in_sizes, int n_in,
                              void* d_out, int out_size, void* d_ws, size_t ws_size,
                              hipStream_t stream) {
    const float* dist = (const float*)d_in[0];
    float* out = (float*)d_out;

    float* scorebuf = (float*)d_ws;                         // 50176 floats
    float* At       = (float*)((char*)d_ws + 50176 * 4);    // 56*224 floats

    topk_score_kernel<<<NBLK_TOPK + NBLK_AT, 256, 0, stream>>>(dist, scorebuf, At);
    post_kernel<<<NB * OH, 256, 0, stream>>>(scorebuf, At, out);
}

// Round 6
// 139.739 us; speedup vs baseline: 1.1244x; 1.0065x over previous
//
#include <hip/hip_runtime.h>

// distance: [16, 3136, 4096] f32; score 56x56 -> bilinear resize 224x224 -> gauss sigma=4 (ksize 33)
#define NB   16
#define HW   3136
#define MEL  4096
#define SH   56
#define SW   56
#define OH   224
#define OW   224
#define KRAD 16
#define NROWS (NB * HW)                    // 50176
#define NBLK_TOPK (NROWS / 8)              // 6272 (8 rows/block, 2 rows/wave)
#define NBLK_AT   ((SH * OH + 255) / 256)  // 49

typedef float vf4 __attribute__((ext_vector_type(4)));

// Branchless insert of v into sorted ascending triple (m0 <= m1 <= m2), keeping 3 smallest.
__device__ __forceinline__ void ins3(float v, float& m0, float& m1, float& m2) {
    float a = fminf(v, m0);
    float b = fmaxf(v, m0);
    m0 = a;
    float c = fminf(b, m1);
    float d = fmaxf(b, m1);
    m1 = c;
    m2 = fminf(d, m2);
}

// Reduce one row's loaded batch (16 x vf4) to the softmin score; butterfly + store.
__device__ __forceinline__ void reduce_row(const vf4* __restrict__ v, int lane,
                                           float* __restrict__ dst) {
    float a0 = 3.4e38f, a1 = 3.4e38f, a2 = 3.4e38f;
    float b0 = 3.4e38f, b1 = 3.4e38f, b2 = 3.4e38f;
    #pragma unroll
    for (int j = 0; j < 16; ++j) {
        ins3(v[j][0], a0, a1, a2);
        ins3(v[j][1], b0, b1, b2);
        ins3(v[j][2], a0, a1, a2);
        ins3(v[j][3], b0, b1, b2);
    }
    ins3(b0, a0, a1, a2);
    ins3(b1, a0, a1, a2);
    ins3(b2, a0, a1, a2);
    #pragma unroll
    for (int off = 32; off > 0; off >>= 1) {
        float s0 = __shfl_xor(a0, off);
        float s1 = __shfl_xor(a1, off);
        float s2 = __shfl_xor(a2, off);
        ins3(s0, a0, a1, a2);
        ins3(s1, a0, a1, a2);
        ins3(s2, a0, a1, a2);
    }
    if (lane == 0) {
        float v0 = sqrtf(a0), v1 = sqrtf(a1), v2 = sqrtf(a2);
        *dst = v0 / (1.0f + expf(v0 - v1) + expf(v0 - v2));
    }
}

// Blocks [0, NBLK_TOPK): 8 rows/block, each wave handles 2 consecutive rows with both
// 16-load batches issued up front (32 KB contiguous, 32 loads in flight/wave) so row-B
// loads hide under row-A compute. NT loads (A/B-tested: +0.4 TB/s vs temporal).
// Blocks [NBLK_TOPK, ...): build At[56][224] (gauss∘bilinear operator), rides at grid tail.
__global__ __launch_bounds__(256, 3) void topk_score_kernel(const float* __restrict__ dist,
                                                            float* __restrict__ score,
                                                            float* __restrict__ At) {
    if (blockIdx.x >= NBLK_TOPK) {
        int id = (blockIdx.x - NBLK_TOPK) * 256 + threadIdx.x;
        if (id < SH * OH) {
            int j = id / OH;   // coarse index
            int y = id % OH;   // fine (output) index
            float gsum = 0.0f, acc = 0.0f;
            #pragma unroll
            for (int k = -KRAD; k <= KRAD; ++k) {
                float g = expf((float)(-k * k) * (1.0f / 32.0f));
                gsum += g;
                int f = y + k;                       // reflect at both edges
                f = (f < 0) ? -f : f;
                f = (f > OH - 1) ? (2 * (OH - 1) - f) : f;
                float sy = fmaxf((f + 0.5f) * 0.25f - 0.5f, 0.0f);
                int   y0 = (int)sy;
                float fy = sy - (float)y0;
                int   y1 = min(y0 + 1, SH - 1);
                float w = ((y0 == j) ? (1.0f - fy) : 0.0f) + ((y1 == j) ? fy : 0.0f);
                acc += g * w;
            }
            At[id] = acc / gsum;
        }
        return;
    }

    const int wid  = threadIdx.x >> 6;
    const int lane = threadIdx.x & 63;
    const long long r0 = (long long)blockIdx.x * 8 + wid * 2;   // rows r0, r0+1
    const vf4* p0 = (const vf4*)(dist + r0 * (long long)MEL);
    const vf4* p1 = p0 + (MEL / 4);

    vf4 va[16], vb[16];
    #pragma unroll
    for (int j = 0; j < 16; ++j)
        va[j] = __builtin_nontemporal_load(p0 + lane + 64 * j);
    #pragma unroll
    for (int j = 0; j < 16; ++j)
        vb[j] = __builtin_nontemporal_load(p1 + lane + 64 * j);

    reduce_row(va, lane, score + r0);
    reduce_row(vb, lane, score + r0 + 1);
}

// Fused post-process via the factored operator: out[b] = A . s[b] . A^T.
// One block per output row (b,y). A rows have <=11 nonzeros within window [w, w+11].
__global__ __launch_bounds__(256) void post_kernel(const float* __restrict__ score,
                                                   const float* __restrict__ At,
                                                   float* __restrict__ out) {
    __shared__ float tmp[SW];
    const int b = blockIdx.x / OH;
    const int y = blockIdx.x % OH;
    const int tid = threadIdx.x;
    const float* s = score + b * (SH * SW);

    const int wy = min(max((int)floorf((y - 15.5f) * 0.25f - 0.5f), 0), SH - 12);

    if (tid < SW) {
        float acc = 0.0f;
        #pragma unroll
        for (int t = 0; t < 12; ++t) {
            int j = wy + t;
            acc += At[j * OH + y] * s[j * SW + tid];   // At read is block-uniform
        }
        tmp[tid] = acc;
    }
    __syncthreads();

    if (tid < OW) {
        const int x = tid;
        const int wx = min(max((int)floorf((x - 15.5f) * 0.25f - 0.5f), 0), SH - 12);
        float acc = 0.0f;
        #pragma unroll
        for (int t = 0; t < 12; ++t) {
            int j = wx + t;
            acc += At[j * OH + x] * tmp[j];            // coalesced across x
        }
        out[blockIdx.x * OW + x] = acc;
    }
}

extern "C" void kernel_launch(void* const* d_in, const int* in_sizes, int n_in,
                              void* d_out, int out_size, void* d_ws, size_t ws_size,
                              hipStream_t stream) {
    const float* dist = (const float*)d_in[0];
    float* out = (float*)d_out;

    float* scorebuf = (float*)d_ws;                         // 50176 floats
    float* At       = (float*)((char*)d_ws + 50176 * 4);    // 56*224 floats

    topk_score_kernel<<<NBLK_TOPK + NBLK_AT, 256, 0, stream>>>(dist, scorebuf, At);
    post_kernel<<<NB * OH, 256, 0, stream>>>(scorebuf, At, out);
}